// Round 12
// baseline (261.579 us; speedup 1.0000x reference)
//
#include <hip/hip_runtime.h>
#include <hip/hip_bf16.h>
#include <math.h>

#define B_ 64
#define F_ 512   // feature dim = GEMM K
#define T_ 600
#define M_ 200   // merge_size = GEMM M and N
#define MF 16    // f-rows per merge block

typedef __attribute__((ext_vector_type(8))) short bf16x8_t;  // 8 bf16 = 4 VGPRs (MFMA A/B frag)
typedef __attribute__((ext_vector_type(4))) float f32x4_t;   // MFMA C/D frag

static __device__ __forceinline__ unsigned short f2bf(float v) {
    __hip_bfloat16 h = __float2bfloat16(v);
    return *reinterpret_cast<unsigned short*>(&h);
}
static __device__ __forceinline__ float bf2f(unsigned short u) {
    return __uint_as_float(((unsigned)u) << 16);
}

// ---------------------------------------------------------------------------
// Merge (B,F,T) fp32 -> (B,M,F) bf16, transposed.
// v3: register segment-sums.  Segments align to float4s with period 12:
// task j loads 4 aligned float4s (floats 12j..12j+15) and emits m=4j..4j+3.
// Only the bf16 transpose tile (6.7 KB) lives in LDS -> high occupancy.
// grid: (B_ * F_/MF, 2) = (2048, 2), block 256.
// ---------------------------------------------------------------------------
__global__ __launch_bounds__(256)
void merge_t_kernel(const float* __restrict__ a, const float* __restrict__ b,
                    unsigned short* __restrict__ fa, unsigned short* __restrict__ fb) {
    const float* src = (blockIdx.y == 0) ? a : b;
    unsigned short* dst = (blockIdx.y == 0) ? fa : fb;
    int blk = blockIdx.x;
    int bb  = blk >> 5;            // / (F_/MF = 32)
    int f0  = (blk & 31) * MF;

    __shared__ unsigned short tile[MF][208];    // 6.7 KB  [f][m]

    int t = threadIdx.x;
    const float* rowbase = src + (size_t)(bb * F_ + f0) * T_;

    // MF rows x 50 groups-of-4-segments = 800 tasks
    #pragma unroll
    for (int i = 0; i < 4; ++i) {
        int task = t + i * 256;
        if (task < MF * 50) {
            int r = task / 50;
            int j = task - r * 50;
            const float4* rp = (const float4*)(rowbase + (size_t)r * T_);
            float4 q0 = rp[3 * j];
            float4 q1 = rp[3 * j + 1];
            float4 q2 = rp[3 * j + 2];
            // m = 4j+0: t = 12j+1,2,3   (reference add order preserved)
            float s0 = q0.y + q0.z + q0.w;
            // m = 4j+1: t = 12j+4,5,6
            float s1 = q1.x + q1.y + q1.z;
            // m = 4j+2: t = 12j+7,8,9
            float s2 = q1.w + q2.x + q2.y;
            float s3;
            if (j < 49) {
                // m = 4j+3: t = 12j+10,11,12
                float4 q3 = rp[3 * j + 3];
                s3 = q2.z + q2.w + q3.x;
            } else {
                // m = 199: t in {0, 598, 599}
                s3 = ((const float*)rp)[0] + q2.z + q2.w;
            }
            ushort4 o;
            o.x = f2bf(s0); o.y = f2bf(s1); o.z = f2bf(s2); o.w = f2bf(s3);
            *(ushort4*)&tile[r][4 * j] = o;
        }
    }
    __syncthreads();

    // Transposed write.  Lane pair (t&1) covers 8 f each -> 16B/m/lane.
    int half  = t & 1;
    int mbase = t >> 1;
    #pragma unroll
    for (int it = 0; it < 2; ++it) {
        int m = mbase + it * 128;
        if (m < M_) {
            union { unsigned short s[8]; uint4 q; } u;
            #pragma unroll
            for (int k = 0; k < 8; ++k) u.s[k] = tile[half * 8 + k][m];
            *(uint4*)(dst + (size_t)(bb * M_ + m) * F_ + f0 + half * 8) = u.q;
        }
    }
}

// ---------------------------------------------------------------------------
// Row norms from bf16 (B,M,F): one wave per (b,m); 512 bf16 = 16B/lane
// grid: (B_*M_/4, 2), block 256 (4 waves)
// ---------------------------------------------------------------------------
__global__ __launch_bounds__(256)
void norm_kernel(const unsigned short* __restrict__ fa, const unsigned short* __restrict__ fb,
                 float* __restrict__ na, float* __restrict__ nb) {
    const unsigned short* src = (blockIdx.y == 0) ? fa : fb;
    float*                dst = (blockIdx.y == 0) ? na : nb;
    int wave = threadIdx.x >> 6;
    int lane = threadIdx.x & 63;
    int bm = blockIdx.x * 4 + wave;
    const ushort4* p = (const ushort4*)(src + (size_t)bm * F_ + lane * 8);
    ushort4 u0 = p[0], u1 = p[1];
    float acc = 0.f;
    float x;
    x = bf2f(u0.x); acc = fmaf(x, x, acc);
    x = bf2f(u0.y); acc = fmaf(x, x, acc);
    x = bf2f(u0.z); acc = fmaf(x, x, acc);
    x = bf2f(u0.w); acc = fmaf(x, x, acc);
    x = bf2f(u1.x); acc = fmaf(x, x, acc);
    x = bf2f(u1.y); acc = fmaf(x, x, acc);
    x = bf2f(u1.z); acc = fmaf(x, x, acc);
    x = bf2f(u1.w); acc = fmaf(x, x, acc);
    #pragma unroll
    for (int off = 32; off >= 1; off >>= 1)
        acc += __shfl_xor(acc, off, 64);
    if (lane == 0) dst[bm] = sqrtf(acc);
}

// ---------------------------------------------------------------------------
// Batched MFMA GEMM: C[b,m,n] = sum_f fa[b,m,f] * fb[b,n,f]
// 64x64 tile, BK=64, 4 waves (2x2), each wave 32x32 via 2x2 mfma_16x16x32 frags
// ---------------------------------------------------------------------------
#define BK_ 64
__global__ __launch_bounds__(256)
void gemm_kernel(const unsigned short* __restrict__ fa, const unsigned short* __restrict__ fb,
                 float* __restrict__ num) {
    __shared__ unsigned short As[64][88];   // [m][k], padded rows
    __shared__ unsigned short Bs[64][88];   // [n][k]

    int bb = blockIdx.z;
    int m0 = blockIdx.x * 64;
    int n0 = blockIdx.y * 64;
    const unsigned short* A = fa + (size_t)bb * M_ * F_;
    const unsigned short* B = fb + (size_t)bb * M_ * F_;

    int t    = threadIdx.x;
    int lane = t & 63;
    int wid  = t >> 6;           // 0..3
    int wm32 = (wid >> 1) * 32;  // wave m-offset in tile
    int wn32 = (wid & 1) * 32;   // wave n-offset in tile

    int sr = t >> 3;             // staging row 0..31
    int sc = (t & 7) * 8;        // staging col (bf16 index)

    f32x4_t acc[2][2];
    #pragma unroll
    for (int i = 0; i < 2; ++i)
        #pragma unroll
        for (int j = 0; j < 2; ++j)
            acc[i][j] = (f32x4_t)(0.f);

    const uint4 z4 = make_uint4(0, 0, 0, 0);
    for (int k0 = 0; k0 < F_; k0 += BK_) {
        #pragma unroll
        for (int p = 0; p < 2; ++p) {
            int r  = p * 32 + sr;
            int gm = m0 + r, gn = n0 + r;
            uint4 va = z4, vb = z4;
            if (gm < M_) va = *(const uint4*)(A + (size_t)gm * F_ + k0 + sc);
            if (gn < M_) vb = *(const uint4*)(B + (size_t)gn * F_ + k0 + sc);
            *(uint4*)&As[r][sc] = va;
            *(uint4*)&Bs[r][sc] = vb;
        }
        __syncthreads();
        #pragma unroll
        for (int kk = 0; kk < 2; ++kk) {
            int kc = kk * 32 + (lane >> 4) * 8;   // 8 contiguous bf16 per lane
            int rl = lane & 15;
            bf16x8_t a0 = *(const bf16x8_t*)&As[wm32 + rl][kc];
            bf16x8_t a1 = *(const bf16x8_t*)&As[wm32 + 16 + rl][kc];
            bf16x8_t b0 = *(const bf16x8_t*)&Bs[wn32 + rl][kc];
            bf16x8_t b1 = *(const bf16x8_t*)&Bs[wn32 + 16 + rl][kc];
            acc[0][0] = __builtin_amdgcn_mfma_f32_16x16x32_bf16(a0, b0, acc[0][0], 0, 0, 0);
            acc[0][1] = __builtin_amdgcn_mfma_f32_16x16x32_bf16(a0, b1, acc[0][1], 0, 0, 0);
            acc[1][0] = __builtin_amdgcn_mfma_f32_16x16x32_bf16(a1, b0, acc[1][0], 0, 0, 0);
            acc[1][1] = __builtin_amdgcn_mfma_f32_16x16x32_bf16(a1, b1, acc[1][1], 0, 0, 0);
        }
        __syncthreads();
    }

    // C/D layout (m89-verified): col = lane&15, row = (lane>>4)*4 + reg
    float* C = num + (size_t)bb * M_ * M_;
    int r0 = (lane >> 4) * 4;
    int cc = lane & 15;
    #pragma unroll
    for (int i = 0; i < 2; ++i) {
        #pragma unroll
        for (int j = 0; j < 2; ++j) {
            #pragma unroll
            for (int r = 0; r < 4; ++r) {
                int m = m0 + wm32 + i * 16 + r0 + r;
                int n = n0 + wn32 + j * 16 + cc;
                if (m < M_ && n < M_) C[(size_t)m * M_ + n] = acc[i][j][r];
            }
        }
    }
}

// ---------------------------------------------------------------------------
// cosine + log-softmax + diag: 4 waves per block, one (b,m) row per wave
// ---------------------------------------------------------------------------
__global__ __launch_bounds__(256)
void row_softmax_kernel(const float* __restrict__ num,
                        const float* __restrict__ na,
                        const float* __restrict__ nb,
                        float* __restrict__ partial) {
    int wave = threadIdx.x >> 6;
    int lane = threadIdx.x & 63;
    int bm = blockIdx.x * 4 + wave;    // b*M + m
    int b  = bm / M_;
    int m  = bm - b * M_;
    const float* row = num + (size_t)b * M_ * M_ + (size_t)m * M_;
    const float* nbp = nb + b * M_;
    float nam = na[bm];

    float cosv[4];
    float mx = -INFINITY;
    #pragma unroll
    for (int r = 0; r < 4; ++r) {
        int n = lane + r * 64;
        float c = -INFINITY;
        if (n < M_) {
            float denom = fmaxf(nam * nbp[n], 1e-8f);
            c = row[n] / denom;
        }
        cosv[r] = c;
        mx = fmaxf(mx, c);
    }
    #pragma unroll
    for (int off = 32; off >= 1; off >>= 1)
        mx = fmaxf(mx, __shfl_xor(mx, off, 64));

    float s = 0.f, diag = 0.f;
    #pragma unroll
    for (int r = 0; r < 4; ++r) {
        int n = lane + r * 64;
        if (n < M_) {
            s += __expf(cosv[r] - mx);
            if (n == m) diag = cosv[r];
        }
    }
    #pragma unroll
    for (int off = 32; off >= 1; off >>= 1) {
        s    += __shfl_xor(s, off, 64);
        diag += __shfl_xor(diag, off, 64);
    }
    if (lane == 0) {
        float lse = mx + __logf(s);
        partial[bm] = -(diag - lse) / (float)M_;
    }
}

__global__ __launch_bounds__(256)
void final_reduce_kernel(const float* __restrict__ partial, float* __restrict__ out, int n) {
    __shared__ float sm[256];
    float acc = 0.f;
    for (int i = threadIdx.x; i < n; i += 256) acc += partial[i];
    sm[threadIdx.x] = acc;
    __syncthreads();
    #pragma unroll
    for (int st = 128; st > 0; st >>= 1) {
        if (threadIdx.x < st) sm[threadIdx.x] += sm[threadIdx.x + st];
        __syncthreads();
    }
    if (threadIdx.x == 0) out[0] = sm[0];
}

extern "C" void kernel_launch(void* const* d_in, const int* in_sizes, int n_in,
                              void* d_out, int out_size, void* d_ws, size_t ws_size,
                              hipStream_t stream) {
    // d_in[0] = data_label (int64) -- unused by the loss
    const float* a_in = (const float*)d_in[1];
    const float* b_in = (const float*)d_in[2];

    const size_t merged_elems = (size_t)B_ * M_ * F_;         // 6,553,600
    unsigned short* fa = (unsigned short*)d_ws;               // bf16 (B,M,F)
    unsigned short* fb = fa + merged_elems;
    float* num     = (float*)(fb + merged_elems);             // B*M*M fp32
    float* na      = num + (size_t)B_ * M_ * M_;
    float* nb      = na + B_ * M_;
    float* partial = nb + B_ * M_;                            // B*M

    // 1. merge + transpose + bf16 cast (register segment-sums, small LDS)
    merge_t_kernel<<<dim3(B_ * (F_ / MF), 2), 256, 0, stream>>>(a_in, b_in, fa, fb);
    // 2. row norms
    norm_kernel<<<dim3(B_ * M_ / 4, 2), 256, 0, stream>>>(fa, fb, na, nb);
    // 3. batched MFMA GEMM
    gemm_kernel<<<dim3(4, 4, B_), 256, 0, stream>>>(fa, fb, num);
    // 4. cosine + log-softmax diag (4 rows per block)
    row_softmax_kernel<<<dim3(B_ * M_ / 4), 256, 0, stream>>>(num, na, nb, partial);
    // 5. total loss
    final_reduce_kernel<<<1, 256, 0, stream>>>(partial, (float*)d_out, B_ * M_);
}

// Round 13
// 253.138 us; speedup vs baseline: 1.0333x; 1.0333x over previous
//
#include <hip/hip_runtime.h>
#include <hip/hip_bf16.h>
#include <math.h>

#define B_ 64
#define F_ 512   // feature dim = GEMM K
#define T_ 600
#define M_ 200   // merge_size = GEMM M and N

typedef __attribute__((ext_vector_type(8))) short bf16x8_t;  // 8 bf16 = 4 VGPRs (MFMA A/B frag)
typedef __attribute__((ext_vector_type(4))) float f32x4_t;   // MFMA C/D frag

static __device__ __forceinline__ unsigned short f2bf(float v) {
    __hip_bfloat16 h = __float2bfloat16(v);
    return *reinterpret_cast<unsigned short*>(&h);
}
static __device__ __forceinline__ float bf2f(unsigned short u) {
    return __uint_as_float(((unsigned)u) << 16);
}

// ---------------------------------------------------------------------------
// Merge (B,F,T) fp32 -> (B,M,F) bf16, transposed.
// v4: ILP-oriented.  320 threads, 64 f-rows/block -> exactly 10 unguarded
// task iterations per thread (compiler can pipeline the loads).  LDS tile
// 64x210 ushort (26.9 KB, odd-dword row stride -> <=4-way on transpose read).
// Phase 3 writes full 128B f-chunks per m, exact 5 iterations.
// grid: (B_ * F_/64, 2) = (512, 2), block 320.
// ---------------------------------------------------------------------------
__global__ __launch_bounds__(320)
void merge_t_kernel(const float* __restrict__ a, const float* __restrict__ b,
                    unsigned short* __restrict__ fa, unsigned short* __restrict__ fb) {
    const float* src = (blockIdx.y == 0) ? a : b;
    unsigned short* dst = (blockIdx.y == 0) ? fa : fb;
    int blk = blockIdx.x;
    int bb  = blk >> 3;            // / (F_/64 = 8)
    int f0  = (blk & 7) * 64;

    __shared__ unsigned short tile[64][210];    // 26.9 KB, 420B row stride (odd dwords)

    int t = threadIdx.x;
    const float* rowbase = src + (size_t)(bb * F_ + f0) * T_;

    // 64 rows x 50 groups-of-4-segments = 3200 tasks; 10 per thread, no guard
    #pragma unroll 5
    for (int i = 0; i < 10; ++i) {
        int task = t + i * 320;
        int r = task / 50;
        int j = task - r * 50;
        const float4* rp = (const float4*)(rowbase + (size_t)r * T_);
        float4 q0 = rp[3 * j];
        float4 q1 = rp[3 * j + 1];
        float4 q2 = rp[3 * j + 2];
        // m = 4j+0: t = 12j+1,2,3   (reference add order preserved)
        float s0 = q0.y + q0.z + q0.w;
        // m = 4j+1: t = 12j+4,5,6
        float s1 = q1.x + q1.y + q1.z;
        // m = 4j+2: t = 12j+7,8,9
        float s2 = q1.w + q2.x + q2.y;
        float s3;
        if (j < 49) {
            // m = 4j+3: t = 12j+10,11,12
            float4 q3 = rp[3 * j + 3];
            s3 = q2.z + q2.w + q3.x;
        } else {
            // m = 199: t in {0, 598, 599}
            s3 = ((const float*)rp)[0] + q2.z + q2.w;
        }
        ushort2 p01 = make_ushort2(f2bf(s0), f2bf(s1));
        ushort2 p23 = make_ushort2(f2bf(s2), f2bf(s3));
        *(ushort2*)&tile[r][4 * j]     = p01;   // 4B stores (row stride is odd-dword)
        *(ushort2*)&tile[r][4 * j + 2] = p23;
    }
    __syncthreads();

    // Transposed write: 40 m-groups x 8 lanes; each lane writes 8 f = 16B.
    // m = grp + it*40, it<5 exact (200 = 40*5).  Per m: 64 f = 128B contiguous.
    int lane8 = t & 7;
    int grp   = t >> 3;            // 0..39
    #pragma unroll
    for (int it = 0; it < 5; ++it) {
        int m = grp + it * 40;
        union { unsigned short s[8]; uint4 q; } u;
        #pragma unroll
        for (int k = 0; k < 8; ++k) u.s[k] = tile[lane8 * 8 + k][m];
        *(uint4*)(dst + (size_t)(bb * M_ + m) * F_ + f0 + lane8 * 8) = u.q;
    }
}

// ---------------------------------------------------------------------------
// Row norms from bf16 (B,M,F): one wave per (b,m); 512 bf16 = 16B/lane
// grid: (B_*M_/4, 2), block 256 (4 waves)
// ---------------------------------------------------------------------------
__global__ __launch_bounds__(256)
void norm_kernel(const unsigned short* __restrict__ fa, const unsigned short* __restrict__ fb,
                 float* __restrict__ na, float* __restrict__ nb) {
    const unsigned short* src = (blockIdx.y == 0) ? fa : fb;
    float*                dst = (blockIdx.y == 0) ? na : nb;
    int wave = threadIdx.x >> 6;
    int lane = threadIdx.x & 63;
    int bm = blockIdx.x * 4 + wave;
    const ushort4* p = (const ushort4*)(src + (size_t)bm * F_ + lane * 8);
    ushort4 u0 = p[0], u1 = p[1];
    float acc = 0.f;
    float x;
    x = bf2f(u0.x); acc = fmaf(x, x, acc);
    x = bf2f(u0.y); acc = fmaf(x, x, acc);
    x = bf2f(u0.z); acc = fmaf(x, x, acc);
    x = bf2f(u0.w); acc = fmaf(x, x, acc);
    x = bf2f(u1.x); acc = fmaf(x, x, acc);
    x = bf2f(u1.y); acc = fmaf(x, x, acc);
    x = bf2f(u1.z); acc = fmaf(x, x, acc);
    x = bf2f(u1.w); acc = fmaf(x, x, acc);
    #pragma unroll
    for (int off = 32; off >= 1; off >>= 1)
        acc += __shfl_xor(acc, off, 64);
    if (lane == 0) dst[bm] = sqrtf(acc);
}

// ---------------------------------------------------------------------------
// Batched MFMA GEMM: C[b,m,n] = sum_f fa[b,m,f] * fb[b,n,f]
// 64x64 tile, BK=64, 4 waves (2x2), each wave 32x32 via 2x2 mfma_16x16x32 frags
// ---------------------------------------------------------------------------
#define BK_ 64
__global__ __launch_bounds__(256)
void gemm_kernel(const unsigned short* __restrict__ fa, const unsigned short* __restrict__ fb,
                 float* __restrict__ num) {
    __shared__ unsigned short As[64][88];   // [m][k], padded rows
    __shared__ unsigned short Bs[64][88];   // [n][k]

    int bb = blockIdx.z;
    int m0 = blockIdx.x * 64;
    int n0 = blockIdx.y * 64;
    const unsigned short* A = fa + (size_t)bb * M_ * F_;
    const unsigned short* B = fb + (size_t)bb * M_ * F_;

    int t    = threadIdx.x;
    int lane = t & 63;
    int wid  = t >> 6;           // 0..3
    int wm32 = (wid >> 1) * 32;  // wave m-offset in tile
    int wn32 = (wid & 1) * 32;   // wave n-offset in tile

    int sr = t >> 3;             // staging row 0..31
    int sc = (t & 7) * 8;        // staging col (bf16 index)

    f32x4_t acc[2][2];
    #pragma unroll
    for (int i = 0; i < 2; ++i)
        #pragma unroll
        for (int j = 0; j < 2; ++j)
            acc[i][j] = (f32x4_t)(0.f);

    const uint4 z4 = make_uint4(0, 0, 0, 0);
    for (int k0 = 0; k0 < F_; k0 += BK_) {
        #pragma unroll
        for (int p = 0; p < 2; ++p) {
            int r  = p * 32 + sr;
            int gm = m0 + r, gn = n0 + r;
            uint4 va = z4, vb = z4;
            if (gm < M_) va = *(const uint4*)(A + (size_t)gm * F_ + k0 + sc);
            if (gn < M_) vb = *(const uint4*)(B + (size_t)gn * F_ + k0 + sc);
            *(uint4*)&As[r][sc] = va;
            *(uint4*)&Bs[r][sc] = vb;
        }
        __syncthreads();
        #pragma unroll
        for (int kk = 0; kk < 2; ++kk) {
            int kc = kk * 32 + (lane >> 4) * 8;   // 8 contiguous bf16 per lane
            int rl = lane & 15;
            bf16x8_t a0 = *(const bf16x8_t*)&As[wm32 + rl][kc];
            bf16x8_t a1 = *(const bf16x8_t*)&As[wm32 + 16 + rl][kc];
            bf16x8_t b0 = *(const bf16x8_t*)&Bs[wn32 + rl][kc];
            bf16x8_t b1 = *(const bf16x8_t*)&Bs[wn32 + 16 + rl][kc];
            acc[0][0] = __builtin_amdgcn_mfma_f32_16x16x32_bf16(a0, b0, acc[0][0], 0, 0, 0);
            acc[0][1] = __builtin_amdgcn_mfma_f32_16x16x32_bf16(a0, b1, acc[0][1], 0, 0, 0);
            acc[1][0] = __builtin_amdgcn_mfma_f32_16x16x32_bf16(a1, b0, acc[1][0], 0, 0, 0);
            acc[1][1] = __builtin_amdgcn_mfma_f32_16x16x32_bf16(a1, b1, acc[1][1], 0, 0, 0);
        }
        __syncthreads();
    }

    // C/D layout (m89-verified): col = lane&15, row = (lane>>4)*4 + reg
    float* C = num + (size_t)bb * M_ * M_;
    int r0 = (lane >> 4) * 4;
    int cc = lane & 15;
    #pragma unroll
    for (int i = 0; i < 2; ++i) {
        #pragma unroll
        for (int j = 0; j < 2; ++j) {
            #pragma unroll
            for (int r = 0; r < 4; ++r) {
                int m = m0 + wm32 + i * 16 + r0 + r;
                int n = n0 + wn32 + j * 16 + cc;
                if (m < M_ && n < M_) C[(size_t)m * M_ + n] = acc[i][j][r];
            }
        }
    }
}

// ---------------------------------------------------------------------------
// cosine + log-softmax + diag: 4 waves per block, one (b,m) row per wave
// ---------------------------------------------------------------------------
__global__ __launch_bounds__(256)
void row_softmax_kernel(const float* __restrict__ num,
                        const float* __restrict__ na,
                        const float* __restrict__ nb,
                        float* __restrict__ partial) {
    int wave = threadIdx.x >> 6;
    int lane = threadIdx.x & 63;
    int bm = blockIdx.x * 4 + wave;    // b*M + m
    int b  = bm / M_;
    int m  = bm - b * M_;
    const float* row = num + (size_t)b * M_ * M_ + (size_t)m * M_;
    const float* nbp = nb + b * M_;
    float nam = na[bm];

    float cosv[4];
    float mx = -INFINITY;
    #pragma unroll
    for (int r = 0; r < 4; ++r) {
        int n = lane + r * 64;
        float c = -INFINITY;
        if (n < M_) {
            float denom = fmaxf(nam * nbp[n], 1e-8f);
            c = row[n] / denom;
        }
        cosv[r] = c;
        mx = fmaxf(mx, c);
    }
    #pragma unroll
    for (int off = 32; off >= 1; off >>= 1)
        mx = fmaxf(mx, __shfl_xor(mx, off, 64));

    float s = 0.f, diag = 0.f;
    #pragma unroll
    for (int r = 0; r < 4; ++r) {
        int n = lane + r * 64;
        if (n < M_) {
            s += __expf(cosv[r] - mx);
            if (n == m) diag = cosv[r];
        }
    }
    #pragma unroll
    for (int off = 32; off >= 1; off >>= 1) {
        s    += __shfl_xor(s, off, 64);
        diag += __shfl_xor(diag, off, 64);
    }
    if (lane == 0) {
        float lse = mx + __logf(s);
        partial[bm] = -(diag - lse) / (float)M_;
    }
}

__global__ __launch_bounds__(256)
void final_reduce_kernel(const float* __restrict__ partial, float* __restrict__ out, int n) {
    __shared__ float sm[256];
    float acc = 0.f;
    for (int i = threadIdx.x; i < n; i += 256) acc += partial[i];
    sm[threadIdx.x] = acc;
    __syncthreads();
    #pragma unroll
    for (int st = 128; st > 0; st >>= 1) {
        if (threadIdx.x < st) sm[threadIdx.x] += sm[threadIdx.x + st];
        __syncthreads();
    }
    if (threadIdx.x == 0) out[0] = sm[0];
}

extern "C" void kernel_launch(void* const* d_in, const int* in_sizes, int n_in,
                              void* d_out, int out_size, void* d_ws, size_t ws_size,
                              hipStream_t stream) {
    // d_in[0] = data_label (int64) -- unused by the loss
    const float* a_in = (const float*)d_in[1];
    const float* b_in = (const float*)d_in[2];

    const size_t merged_elems = (size_t)B_ * M_ * F_;         // 6,553,600
    unsigned short* fa = (unsigned short*)d_ws;               // bf16 (B,M,F)
    unsigned short* fb = fa + merged_elems;
    float* num     = (float*)(fb + merged_elems);             // B*M*M fp32
    float* na      = num + (size_t)B_ * M_ * M_;
    float* nb      = na + B_ * M_;
    float* partial = nb + B_ * M_;                            // B*M

    // 1. merge + transpose + bf16 cast (ILP-deep, 10 iters/thread)
    merge_t_kernel<<<dim3(B_ * (F_ / 64), 2), 320, 0, stream>>>(a_in, b_in, fa, fb);
    // 2. row norms
    norm_kernel<<<dim3(B_ * M_ / 4, 2), 256, 0, stream>>>(fa, fb, na, nb);
    // 3. batched MFMA GEMM
    gemm_kernel<<<dim3(4, 4, B_), 256, 0, stream>>>(fa, fb, num);
    // 4. cosine + log-softmax diag (4 rows per block)
    row_softmax_kernel<<<dim3(B_ * M_ / 4), 256, 0, stream>>>(num, na, nb, partial);
    // 5. total loss
    final_reduce_kernel<<<1, 256, 0, stream>>>(partial, (float*)d_out, B_ * M_);
}

// Round 15
// 249.244 us; speedup vs baseline: 1.0495x; 1.0156x over previous
//
#include <hip/hip_runtime.h>
#include <hip/hip_bf16.h>
#include <math.h>

#define B_ 64
#define F_ 512   // feature dim = GEMM K
#define T_ 600
#define M_ 200   // merge_size = GEMM M and N
#define NFRAG 13 // 208 = 13*16 padded n-columns

typedef __attribute__((ext_vector_type(8))) short bf16x8_t;
typedef __attribute__((ext_vector_type(4))) float f32x4_t;

static __device__ __forceinline__ unsigned short f2bf(float v) {
    __hip_bfloat16 h = __float2bfloat16(v);
    return *reinterpret_cast<unsigned short*>(&h);
}
static __device__ __forceinline__ float bf2f(unsigned short u) {
    return __uint_as_float(((unsigned)u) << 16);
}
static __device__ __forceinline__ float ssq8(uint4 v) {
    const unsigned short* s = (const unsigned short*)&v;
    float a = 0.f;
    #pragma unroll
    for (int i = 0; i < 8; ++i) { float x = bf2f(s[i]); a = fmaf(x, x, a); }
    return a;
}

// ---------------------------------------------------------------------------
// Merge (B,F,T) fp32 -> (B,M,F) bf16, transposed.  (v4, measured 69 us)
// Also zeroes d_out for the fused kernel's atomicAdd.
// grid: (B_ * F_/64, 2) = (512, 2), block 320.
// ---------------------------------------------------------------------------
__global__ __launch_bounds__(320)
void merge_t_kernel(const float* __restrict__ a, const float* __restrict__ b,
                    unsigned short* __restrict__ fa, unsigned short* __restrict__ fb,
                    float* __restrict__ out) {
    if (blockIdx.x == 0 && blockIdx.y == 0 && threadIdx.x == 0) out[0] = 0.f;

    const float* src = (blockIdx.y == 0) ? a : b;
    unsigned short* dst = (blockIdx.y == 0) ? fa : fb;
    int blk = blockIdx.x;
    int bb  = blk >> 3;            // / (F_/64 = 8)
    int f0  = (blk & 7) * 64;

    __shared__ unsigned short tile[64][210];    // 26.9 KB

    int t = threadIdx.x;
    const float* rowbase = src + (size_t)(bb * F_ + f0) * T_;

    #pragma unroll 5
    for (int i = 0; i < 10; ++i) {
        int task = t + i * 320;
        int r = task / 50;
        int j = task - r * 50;
        const float4* rp = (const float4*)(rowbase + (size_t)r * T_);
        float4 q0 = rp[3 * j];
        float4 q1 = rp[3 * j + 1];
        float4 q2 = rp[3 * j + 2];
        float s0 = q0.y + q0.z + q0.w;          // m=4j+0: t=12j+1..3
        float s1 = q1.x + q1.y + q1.z;          // m=4j+1
        float s2 = q1.w + q2.x + q2.y;          // m=4j+2
        float s3;
        if (j < 49) {
            float4 q3 = rp[3 * j + 3];
            s3 = q2.z + q2.w + q3.x;            // m=4j+3
        } else {
            s3 = ((const float*)rp)[0] + q2.z + q2.w;  // m=199: {0,598,599}
        }
        ushort2 p01 = make_ushort2(f2bf(s0), f2bf(s1));
        ushort2 p23 = make_ushort2(f2bf(s2), f2bf(s3));
        *(ushort2*)&tile[r][4 * j]     = p01;
        *(ushort2*)&tile[r][4 * j + 2] = p23;
    }
    __syncthreads();

    int lane8 = t & 7;
    int grp   = t >> 3;            // 0..39
    #pragma unroll
    for (int it = 0; it < 5; ++it) {
        int m = grp + it * 40;
        union { unsigned short s[8]; uint4 q; } u;
        #pragma unroll
        for (int k = 0; k < 8; ++k) u.s[k] = tile[lane8 * 8 + k][m];
        *(uint4*)(dst + (size_t)(bb * M_ + m) * F_ + f0 + lane8 * 8) = u.q;
    }
}

// ---------------------------------------------------------------------------
// Fused: norms + batched MFMA GEMM + cosine + row log-softmax + diag + loss.
// grid: (4, B_) = 256 blocks (1/CU), 256 threads = 4 waves.
// Block = 64 m-rows x all 208 n-cols.  Wave = 16 m x 208 n (13 frags).
// na/nb sumsq accumulated during staging; epilogue in-register on the
// m89-verified C/D layout: col = lane&15, row = (lane>>4)*4 + reg.
// ---------------------------------------------------------------------------
__global__ __launch_bounds__(256)
void fused_loss_kernel(const unsigned short* __restrict__ fa,
                       const unsigned short* __restrict__ fb,
                       float* __restrict__ out) {
    __shared__ unsigned short As[64][88];    // 11.3 KB
    __shared__ unsigned short Bs[208][88];   // 36.6 KB
    __shared__ float na_sq[64];
    __shared__ float nb_sq[208];
    __shared__ float wloss[4];

    int bb = blockIdx.y;
    int m0 = blockIdx.x * 64;
    const unsigned short* A  = fa + (size_t)bb * M_ * F_;
    const unsigned short* Bp = fb + (size_t)bb * M_ * F_;

    int t    = threadIdx.x;
    int lane = t & 63;
    int wave = t >> 6;
    int g    = lane >> 4;      // 0..3
    int c    = lane & 15;      // frag col

    if (t < 64)  na_sq[t] = 0.f;
    if (t < 208) nb_sq[t] = 0.f;
    __syncthreads();

    f32x4_t acc[NFRAG];
    #pragma unroll
    for (int f = 0; f < NFRAG; ++f) acc[f] = (f32x4_t)(0.f);

    // A staging map: idx = t + 256*i (i=0,1) -> row = idx>>3 (0..63), kq = t&7
    float assq0 = 0.f, assq1 = 0.f;
    const uint4 z4 = make_uint4(0, 0, 0, 0);

    for (int k0 = 0; k0 < F_; k0 += 64) {
        // stage A (64 x 64) + sumsq
        {
            int ar0 = t >> 3, kq = t & 7;
            int gm0 = m0 + ar0;
            uint4 v0 = z4;
            if (gm0 < M_) v0 = *(const uint4*)(A + (size_t)gm0 * F_ + k0 + kq * 8);
            *(uint4*)&As[ar0][kq * 8] = v0;
            assq0 += ssq8(v0);
            int ar1 = ar0 + 32;
            int gm1 = m0 + ar1;
            uint4 v1 = z4;
            if (gm1 < M_) v1 = *(const uint4*)(A + (size_t)gm1 * F_ + k0 + kq * 8);
            *(uint4*)&As[ar1][kq * 8] = v1;
            assq1 += ssq8(v1);
        }
        // stage B (208 x 64, rows >=200 zero) + sumsq via LDS atomics
        #pragma unroll
        for (int i = 0; i < 7; ++i) {
            int idx = t + (i << 8);
            if (idx < 1664) {
                int br = idx >> 3, kq = idx & 7;
                uint4 v = z4;
                if (br < M_) v = *(const uint4*)(Bp + (size_t)br * F_ + k0 + kq * 8);
                *(uint4*)&Bs[br][kq * 8] = v;
                if (br < M_) atomicAdd(&nb_sq[br], ssq8(v));
            }
        }
        __syncthreads();
        #pragma unroll
        for (int kk = 0; kk < 2; ++kk) {
            int kc = kk * 32 + g * 8;
            bf16x8_t af = *(const bf16x8_t*)&As[wave * 16 + c][kc];
            #pragma unroll
            for (int f = 0; f < NFRAG; ++f) {
                bf16x8_t bfr = *(const bf16x8_t*)&Bs[f * 16 + c][kc];
                acc[f] = __builtin_amdgcn_mfma_f32_16x16x32_bf16(af, bfr, acc[f], 0, 0, 0);
            }
        }
        __syncthreads();
    }

    // finish na: reduce over kq (8 consecutive lanes share a row)
    #pragma unroll
    for (int off = 1; off <= 4; off <<= 1) {
        assq0 += __shfl_xor(assq0, off, 64);
        assq1 += __shfl_xor(assq1, off, 64);
    }
    if ((t & 7) == 0) {
        na_sq[t >> 3]        = assq0;
        na_sq[32 + (t >> 3)] = assq1;
    }
    __syncthreads();

    // ---- epilogue: cosine + row log-softmax + diag ----
    int m0w = m0 + wave * 16;
    float na_r[4];
    #pragma unroll
    for (int r = 0; r < 4; ++r) na_r[r] = sqrtf(na_sq[wave * 16 + g * 4 + r]);

    float mx[4] = {-INFINITY, -INFINITY, -INFINITY, -INFINITY};
    float diag_cos[4] = {0.f, 0.f, 0.f, 0.f};
    int f_diag = m0w >> 4;   // uniform per wave; valid only when row<200

    #pragma unroll
    for (int f = 0; f < NFRAG; ++f) {
        float nbv = sqrtf(nb_sq[f * 16 + c]);
        int col = f * 16 + c;
        bool colok = (col < M_);
        #pragma unroll
        for (int r = 0; r < 4; ++r) {
            float denom = fmaxf(na_r[r] * nbv, 1e-8f);
            float cv = acc[f][r] / denom;
            int row = m0w + g * 4 + r;
            if (f == f_diag && row < M_ && c == g * 4 + r) diag_cos[r] = cv;
            cv = colok ? cv : -INFINITY;
            acc[f][r] = cv;
            mx[r] = fmaxf(mx[r], cv);
        }
    }
    #pragma unroll
    for (int off = 1; off <= 8; off <<= 1)
        #pragma unroll
        for (int r = 0; r < 4; ++r)
            mx[r] = fmaxf(mx[r], __shfl_xor(mx[r], off, 64));

    float sm[4] = {0.f, 0.f, 0.f, 0.f};
    #pragma unroll
    for (int f = 0; f < NFRAG; ++f)
        #pragma unroll
        for (int r = 0; r < 4; ++r)
            sm[r] += __expf(acc[f][r] - mx[r]);   // -inf cols -> 0
    #pragma unroll
    for (int off = 1; off <= 8; off <<= 1)
        #pragma unroll
        for (int r = 0; r < 4; ++r)
            sm[r] += __shfl_xor(sm[r], off, 64);

    float loss = 0.f;
    #pragma unroll
    for (int r = 0; r < 4; ++r) {
        int row = m0w + g * 4 + r;
        if (row < M_ && c == g * 4 + r) {
            float lse = mx[r] + __logf(sm[r]);
            loss -= (diag_cos[r] - lse) * (1.0f / (float)M_);
        }
    }
    #pragma unroll
    for (int off = 1; off <= 32; off <<= 1)
        loss += __shfl_xor(loss, off, 64);
    if (lane == 0) wloss[wave] = loss;
    __syncthreads();
    if (t == 0) atomicAdd(out, wloss[0] + wloss[1] + wloss[2] + wloss[3]);
}

extern "C" void kernel_launch(void* const* d_in, const int* in_sizes, int n_in,
                              void* d_out, int out_size, void* d_ws, size_t ws_size,
                              hipStream_t stream) {
    // d_in[0] = data_label (int64) -- unused by the loss
    const float* a_in = (const float*)d_in[1];
    const float* b_in = (const float*)d_in[2];

    const size_t merged_elems = (size_t)B_ * M_ * F_;   // 6,553,600
    unsigned short* fa = (unsigned short*)d_ws;         // bf16 (B,M,F)
    unsigned short* fb = fa + merged_elems;
    float* out = (float*)d_out;

    // 1. merge + transpose + bf16 cast (also zeroes out[0])
    merge_t_kernel<<<dim3(B_ * (F_ / 64), 2), 320, 0, stream>>>(a_in, b_in, fa, fb, out);
    // 2. fused norms + GEMM + cosine + log-softmax + diag + loss
    fused_loss_kernel<<<dim3(4, B_), 256, 0, stream>>>(fa, fb, out);
}